// Round 5
// baseline (203.869 us; speedup 1.0000x reference)
//
#include <hip/hip_runtime.h>
#include <hip/hip_bf16.h>

// y[i, d] = x[i, d] * A_diag[d] + B[d]
// N = 262144 rows, D = 512 fp32. HBM-bound streaming FMA.
//
// R5: same structure as R4 (no LDS, register-held a/b, contiguous-chunk
// unroll) but 8 independent load->fma->store chains per thread (32KB
// chunk per block-iteration) to double outstanding memory per wave.
// Grid 2048 x 256: exactly 8 iterations, no tail.

typedef float f32x4 __attribute__((ext_vector_type(4)));

#define D4 128                          // 512 / 4 float4 columns
constexpr long N4 = 262144L * D4;       // 33,554,432 float4 elements

__global__ __launch_bounds__(256) void diag_affine_kernel(
    const f32x4* __restrict__ x,
    const f32x4* __restrict__ A4,
    const f32x4* __restrict__ B4,
    f32x4* __restrict__ out)
{
    // Chunk bases are multiples of 2048, intra-chunk offsets multiples of
    // 256, so (index & 127) == tid & 127 -> a/b are loop-invariant.
    const int j = threadIdx.x & (D4 - 1);
    const f32x4 a = A4[j];
    const f32x4 b = B4[j];

    const long chunk = 2048;                              // float4s per block-iter (32KB)
    const long step  = (long)gridDim.x * chunk;           // 4,194,304 @ grid=2048

    for (long base = (long)blockIdx.x * chunk + threadIdx.x; base < N4; base += step) {
        f32x4 v0 = x[base];
        f32x4 v1 = x[base +  256];
        f32x4 v2 = x[base +  512];
        f32x4 v3 = x[base +  768];
        f32x4 v4 = x[base + 1024];
        f32x4 v5 = x[base + 1280];
        f32x4 v6 = x[base + 1536];
        f32x4 v7 = x[base + 1792];

        out[base]        = v0 * a + b;
        out[base +  256] = v1 * a + b;
        out[base +  512] = v2 * a + b;
        out[base +  768] = v3 * a + b;
        out[base + 1024] = v4 * a + b;
        out[base + 1280] = v5 * a + b;
        out[base + 1536] = v6 * a + b;
        out[base + 1792] = v7 * a + b;
    }
}

extern "C" void kernel_launch(void* const* d_in, const int* in_sizes, int n_in,
                              void* d_out, int out_size, void* d_ws, size_t ws_size,
                              hipStream_t stream) {
    const float* x = (const float*)d_in[0];
    const float* A = (const float*)d_in[1];
    const float* B = (const float*)d_in[2];
    float* out = (float*)d_out;

    const int block = 256;
    const int grid = 2048;   // 8 exact iterations of 32KB chunks per block

    diag_affine_kernel<<<grid, block, 0, stream>>>(
        reinterpret_cast<const f32x4*>(x),
        reinterpret_cast<const f32x4*>(A),
        reinterpret_cast<const f32x4*>(B),
        reinterpret_cast<f32x4*>(out));
}

// Round 6
// 198.743 us; speedup vs baseline: 1.0258x; 1.0258x over previous
//
#include <hip/hip_runtime.h>
#include <hip/hip_bf16.h>

// y[i, d] = x[i, d] * A_diag[d] + B[d]
// N = 262144 rows, D = 512 fp32. HBM-bound streaming FMA.
//
// R6: R4 geometry (4 chains, 16KB contiguous chunk/block-iter, grid
// 2048x256, no LDS, register-held a/b — R5's 8 chains regressed via the
// VGPR/occupancy cliff) + explicit register double-buffer: iteration
// i+1's loads are issued BEFORE iteration i's stores, so the wave keeps
// 4 loads in flight during the store phase (waitcnt vmcnt(4) instead of
// vmcnt(0) ahead of the stores).

typedef float f32x4 __attribute__((ext_vector_type(4)));

#define D4 128                          // 512 / 4 float4 columns
constexpr long N4 = 262144L * D4;       // 33,554,432 float4 elements

__global__ __launch_bounds__(256) void diag_affine_kernel(
    const f32x4* __restrict__ x,
    const f32x4* __restrict__ A4,
    const f32x4* __restrict__ B4,
    f32x4* __restrict__ out)
{
    // Chunk bases are multiples of 1024, intra-chunk offsets multiples of
    // 256, so (index & 127) == tid & 127 -> a/b are loop-invariant.
    const int j = threadIdx.x & (D4 - 1);
    const f32x4 a = A4[j];
    const f32x4 b = B4[j];

    const long chunk = 1024;                              // float4s per block-iter (16KB)
    const long step  = (long)gridDim.x * chunk;           // 2,097,152 @ grid=2048

    long cur = (long)blockIdx.x * chunk + threadIdx.x;

    // prologue: first chunk's loads
    f32x4 v0 = x[cur];
    f32x4 v1 = x[cur + 256];
    f32x4 v2 = x[cur + 512];
    f32x4 v3 = x[cur + 768];

    for (long nxt = cur + step; nxt < N4; nxt += step) {
        // issue next chunk's loads before current chunk's stores
        f32x4 w0 = x[nxt];
        f32x4 w1 = x[nxt + 256];
        f32x4 w2 = x[nxt + 512];
        f32x4 w3 = x[nxt + 768];

        out[cur]       = v0 * a + b;
        out[cur + 256] = v1 * a + b;
        out[cur + 512] = v2 * a + b;
        out[cur + 768] = v3 * a + b;

        v0 = w0; v1 = w1; v2 = w2; v3 = w3;
        cur = nxt;
    }

    // epilogue: store last chunk
    out[cur]       = v0 * a + b;
    out[cur + 256] = v1 * a + b;
    out[cur + 512] = v2 * a + b;
    out[cur + 768] = v3 * a + b;
}

extern "C" void kernel_launch(void* const* d_in, const int* in_sizes, int n_in,
                              void* d_out, int out_size, void* d_ws, size_t ws_size,
                              hipStream_t stream) {
    const float* x = (const float*)d_in[0];
    const float* A = (const float*)d_in[1];
    const float* B = (const float*)d_in[2];
    float* out = (float*)d_out;

    const int block = 256;
    const int grid = 2048;   // 16 chunks of 16KB per block, no tail

    diag_affine_kernel<<<grid, block, 0, stream>>>(
        reinterpret_cast<const f32x4*>(x),
        reinterpret_cast<const f32x4*>(A),
        reinterpret_cast<const f32x4*>(B),
        reinterpret_cast<f32x4*>(out));
}

// Round 7
// 185.531 us; speedup vs baseline: 1.0988x; 1.0712x over previous
//
#include <hip/hip_runtime.h>
#include <hip/hip_bf16.h>

// y[i, d] = x[i, d] * A_diag[d] + B[d]
// N = 262144 rows, D = 512 fp32. HBM-bound streaming FMA.
//
// R7: ONE-SHOT variant. Each block handles exactly one contiguous 16 KB
// chunk (1024 float4s: 4 wave-segments at +0/+4/+8/+12 KB) and exits —
// no loop. Cross-chunk overlap comes from hardware wave-refill: a wave
// retires after issuing its stores and the CU refills the slot with a
// fresh block whose loads issue immediately, overlapping the previous
// wave's store drain. Grid 32768 x 256 covers the array exactly once.
// A/B (2 KB each) are L1-resident; a/b amortize over 4 chains/thread.

typedef float f32x4 __attribute__((ext_vector_type(4)));

#define D4 128                          // 512 / 4 float4 columns

__global__ __launch_bounds__(256) void diag_affine_kernel(
    const f32x4* __restrict__ x,
    const f32x4* __restrict__ A4,
    const f32x4* __restrict__ B4,
    f32x4* __restrict__ out)
{
    // base is blockIdx*1024 + tid: chunk bases are multiples of 1024 and
    // intra-chunk offsets multiples of 256, so (index & 127) == tid & 127.
    const int j = threadIdx.x & (D4 - 1);
    const f32x4 a = A4[j];
    const f32x4 b = B4[j];

    const long base = (long)blockIdx.x * 1024 + threadIdx.x;

    f32x4 v0 = x[base];
    f32x4 v1 = x[base + 256];
    f32x4 v2 = x[base + 512];
    f32x4 v3 = x[base + 768];

    out[base]       = v0 * a + b;
    out[base + 256] = v1 * a + b;
    out[base + 512] = v2 * a + b;
    out[base + 768] = v3 * a + b;
}

extern "C" void kernel_launch(void* const* d_in, const int* in_sizes, int n_in,
                              void* d_out, int out_size, void* d_ws, size_t ws_size,
                              hipStream_t stream) {
    const float* x = (const float*)d_in[0];
    const float* A = (const float*)d_in[1];
    const float* B = (const float*)d_in[2];
    float* out = (float*)d_out;

    const int block = 256;
    const int grid = 32768;   // (262144*512/4) / 1024 chunks, exact cover

    diag_affine_kernel<<<grid, block, 0, stream>>>(
        reinterpret_cast<const f32x4*>(x),
        reinterpret_cast<const f32x4*>(A),
        reinterpret_cast<const f32x4*>(B),
        reinterpret_cast<f32x4*>(out));
}

// Round 8
// 182.796 us; speedup vs baseline: 1.1153x; 1.0150x over previous
//
#include <hip/hip_runtime.h>
#include <hip/hip_bf16.h>

// y[i, d] = x[i, d] * A_diag[d] + B[d]
// N = 262144 rows, D = 512 fp32. HBM-bound streaming FMA.
//
// R8: finer-grain ONE-SHOT. Each block handles one contiguous 8 KB chunk
// (512 float4s: 2 wave-segments at +0/+4 KB) and exits. Doubling the
// block count (grid 65536) doubles the wave-refill boundaries where the
// HW scheduler overlaps a retiring wave's store drain with a fresh
// wave's loads (the R7 win mechanism). Tradeoff probed: a/b prologue
// loads now amortize over 2 stream chains instead of 4.

typedef float f32x4 __attribute__((ext_vector_type(4)));

#define D4 128                          // 512 / 4 float4 columns

__global__ __launch_bounds__(256) void diag_affine_kernel(
    const f32x4* __restrict__ x,
    const f32x4* __restrict__ A4,
    const f32x4* __restrict__ B4,
    f32x4* __restrict__ out)
{
    // base = blockIdx*512 + tid: chunk bases are multiples of 512 and the
    // +256 offset keeps (index & 127) == tid & 127 -> a/b loop-invariant.
    const int j = threadIdx.x & (D4 - 1);
    const f32x4 a = A4[j];
    const f32x4 b = B4[j];

    const long base = (long)blockIdx.x * 512 + threadIdx.x;

    f32x4 v0 = x[base];
    f32x4 v1 = x[base + 256];

    out[base]       = v0 * a + b;
    out[base + 256] = v1 * a + b;
}

extern "C" void kernel_launch(void* const* d_in, const int* in_sizes, int n_in,
                              void* d_out, int out_size, void* d_ws, size_t ws_size,
                              hipStream_t stream) {
    const float* x = (const float*)d_in[0];
    const float* A = (const float*)d_in[1];
    const float* B = (const float*)d_in[2];
    float* out = (float*)d_out;

    const int block = 256;
    const int grid = 65536;   // (262144*512/4) / 512 chunks, exact cover

    diag_affine_kernel<<<grid, block, 0, stream>>>(
        reinterpret_cast<const f32x4*>(x),
        reinterpret_cast<const f32x4*>(A),
        reinterpret_cast<const f32x4*>(B),
        reinterpret_cast<f32x4*>(out));
}

// Round 9
// 178.297 us; speedup vs baseline: 1.1434x; 1.0252x over previous
//
#include <hip/hip_runtime.h>
#include <hip/hip_bf16.h>

// y[i, d] = x[i, d] * A_diag[d] + B[d]
// N = 262144 rows, D = 512 fp32. HBM-bound streaming FMA.
//
// R9: finest-grain ONE-SHOT. Each block handles one contiguous 4 KB
// chunk (256 float4s, one per thread) and exits. Grid 131072 maximizes
// wave-refill boundaries — the mechanism that won R7 (185.5) and R8
// (182.8): a retiring wave's store drain is overlapped by a fresh
// wave's loads at the HW scheduler level. a/b loads are L1-hits.

typedef float f32x4 __attribute__((ext_vector_type(4)));

#define D4 128                          // 512 / 4 float4 columns

__global__ __launch_bounds__(256) void diag_affine_kernel(
    const f32x4* __restrict__ x,
    const f32x4* __restrict__ A4,
    const f32x4* __restrict__ B4,
    f32x4* __restrict__ out)
{
    // base = blockIdx*256 + tid: chunk bases are multiples of 256, so
    // (index & 127) == tid & 127 -> per-thread a/b fixed.
    const int j = threadIdx.x & (D4 - 1);
    const f32x4 a = A4[j];
    const f32x4 b = B4[j];

    const long base = (long)blockIdx.x * 256 + threadIdx.x;

    f32x4 v = x[base];
    out[base] = v * a + b;
}

extern "C" void kernel_launch(void* const* d_in, const int* in_sizes, int n_in,
                              void* d_out, int out_size, void* d_ws, size_t ws_size,
                              hipStream_t stream) {
    const float* x = (const float*)d_in[0];
    const float* A = (const float*)d_in[1];
    const float* B = (const float*)d_in[2];
    float* out = (float*)d_out;

    const int block = 256;
    const int grid = 131072;   // (262144*512/4) / 256 chunks, exact cover

    diag_affine_kernel<<<grid, block, 0, stream>>>(
        reinterpret_cast<const f32x4*>(x),
        reinterpret_cast<const f32x4*>(A),
        reinterpret_cast<const f32x4*>(B),
        reinterpret_cast<f32x4*>(out));
}

// Round 10
// 176.362 us; speedup vs baseline: 1.1560x; 1.0110x over previous
//
#include <hip/hip_runtime.h>
#include <hip/hip_bf16.h>

// y[i, d] = x[i, d] * A_diag[d] + B[d]
// N = 262144 rows, D = 512 fp32. HBM-bound streaming FMA.
//
// R10: one-shot, one float4 per thread, block=128 (2 waves / 2 KB per
// block), grid 262144. Ladder so far (refill-quantum halvings all won):
// 16KB/185.5 -> 8KB/182.8 -> 4KB/178.3. This halves the block-retire
// quantum again; probing whether CP dispatch rate or WG-slot limits
// flip the trend.

typedef float f32x4 __attribute__((ext_vector_type(4)));

#define D4 128                          // 512 / 4 float4 columns

__global__ __launch_bounds__(128) void diag_affine_kernel(
    const f32x4* __restrict__ x,
    const f32x4* __restrict__ A4,
    const f32x4* __restrict__ B4,
    f32x4* __restrict__ out)
{
    // base = blockIdx*128 + tid, so (base & 127) == tid -> fixed column.
    const int j = threadIdx.x;          // 0..127 == float4 column
    const f32x4 a = A4[j];
    const f32x4 b = B4[j];

    const long base = (long)blockIdx.x * 128 + threadIdx.x;

    f32x4 v = x[base];
    out[base] = v * a + b;
}

extern "C" void kernel_launch(void* const* d_in, const int* in_sizes, int n_in,
                              void* d_out, int out_size, void* d_ws, size_t ws_size,
                              hipStream_t stream) {
    const float* x = (const float*)d_in[0];
    const float* A = (const float*)d_in[1];
    const float* B = (const float*)d_in[2];
    float* out = (float*)d_out;

    const int block = 128;
    const int grid = 262144;   // (262144*512/4) / 128 chunks, exact cover

    diag_affine_kernel<<<grid, block, 0, stream>>>(
        reinterpret_cast<const f32x4*>(x),
        reinterpret_cast<const f32x4*>(A),
        reinterpret_cast<const f32x4*>(B),
        reinterpret_cast<f32x4*>(out));
}